// Round 11
// baseline (391.483 us; speedup 1.0000x reference)
//
#include <hip/hip_runtime.h>
#include <cstddef>

#define HW    4096
#define NPIX  16384
#define CCH   256

typedef __attribute__((ext_vector_type(8))) short bf16x8;
typedef __attribute__((ext_vector_type(4))) float f32x4;

__device__ __forceinline__ float gelu_f(float x){
    return 0.5f * x * (1.0f + erff(x * 0.70710678118654752f));
}

__device__ __forceinline__ unsigned short bf_rne(float f){
    unsigned u = __float_as_uint(f);
    u += 0x7FFFu + ((u >> 16) & 1u);
    return (unsigned short)(u >> 16);
}

// cheap split: hi = trunc_bf16(f), lo = trunc_bf16(f - hi). 4 VALU ops/elem,
// representation error <= 2^-16 relative — far inside tolerance.
__device__ __forceinline__ void split_cheap(const float4 a, const float4 b, bf16x8& hi, bf16x8& lo){
    const float v[8] = {a.x,a.y,a.z,a.w,b.x,b.y,b.z,b.w};
    #pragma unroll
    for (int j = 0; j < 8; j++){
        const unsigned u = __float_as_uint(v[j]);
        hi[j] = (short)(unsigned short)(u >> 16);
        const float r = v[j] - __uint_as_float(u & 0xFFFF0000u);
        lo[j] = (short)(unsigned short)(__float_as_uint(r) >> 16);
    }
}

// ---------------- conv-weight transpose: one tap per block ----------------
__global__ __launch_bounds__(256) void k_prep(const float* __restrict__ w5,
                                              const float* __restrict__ w3,
                                              float* __restrict__ wT,
                                              float* __restrict__ wT3){
    const int c = threadIdx.x;
    const int j = blockIdx.x;
    wT[j * CCH + c] = w5[c * 25 + j];
    if (j < 9) wT3[j * CCH + c] = w3[c * 9 + j];
}

// ---------------- weight composition: woc = outproj_w @ conv_w ; boc = outproj_b @ conv_w + conv_b
// grid 257: blocks 0..255 = one output row each; block 256 = bias row
__global__ __launch_bounds__(256) void k_compose(const float* __restrict__ ow,
                                                 const float* __restrict__ cw,
                                                 const float* __restrict__ ob,
                                                 const float* __restrict__ cb,
                                                 float* __restrict__ woc,
                                                 float* __restrict__ boc){
    const int m = threadIdx.x;
    if (blockIdx.x == 256){
        float acc = cb[m];
        #pragma unroll 4
        for (int k = 0; k < 256; k++) acc = fmaf(ob[k], cw[k * 256 + m], acc);
        boc[m] = acc;
    } else {
        const int r = blockIdx.x;
        const float* orow = ow + r * 256;
        float acc = 0.f;
        #pragma unroll 4
        for (int k = 0; k < 256; k++) acc = fmaf(orow[k], cw[k * 256 + m], acc);
        woc[r * 256 + m] = acc;
    }
}

// ---------------- GEMM-weight prep: W[k][m] fp32 -> W_T[m][k] bf16 hi/lo, LDS-tiled ---------
// grid (16, 5): blockIdx.y = matrix id (0=proj1,1=inproj,2=woc,3=proj2,4=off||mask concat)
__global__ __launch_bounds__(256) void k_prep_w(
    const float* __restrict__ w0, const float* __restrict__ w1, const float* __restrict__ w2,
    const float* __restrict__ w3,
    const float* __restrict__ offw, const float* __restrict__ maskw,
    const float* __restrict__ offb, const float* __restrict__ maskb,
    unsigned short* __restrict__ wsp, float* __restrict__ bcat)
{
    __shared__ float tile[64][65];
    const int id = blockIdx.y;
    const int m0 = (blockIdx.x & 3) * 64;
    const int k0 = (blockIdx.x >> 2) * 64;
    const int tx = threadIdx.x & 63, tg = threadIdx.x >> 6;
    unsigned short* hi = wsp + (size_t)id * 131072;
    unsigned short* lo = hi + 65536;

    const int m = m0 + tx;
    const float* src = nullptr; int stride = 0; bool valid = true;
    if (id == 4){
        if (m < 144){ src = offw + m; stride = 144; }
        else if (m < 216){ src = maskw + (m - 144); stride = 72; }
        else valid = false;
    } else {
        const float* s = (id==0)?w0:(id==1)?w1:(id==2)?w2:w3;
        src = s + m; stride = 256;
    }
    #pragma unroll
    for (int i = 0; i < 16; i++){
        const int kl = tg * 16 + i;
        tile[kl][tx] = valid ? src[(size_t)(k0 + kl) * stride] : 0.f;
    }
    __syncthreads();
    #pragma unroll
    for (int i = 0; i < 16; i++){
        const int ml = tg * 16 + i;
        const float f = tile[tx][ml];
        const unsigned u = __float_as_uint(f);
        const size_t o = (size_t)(m0 + ml) * 256 + k0 + tx;
        hi[o] = (unsigned short)(u >> 16);
        lo[o] = bf_rne(f - __uint_as_float(u & 0xFFFF0000u));
    }
    if (id == 4 && blockIdx.x == 0){
        const int t = threadIdx.x;
        if (t < 216) bcat[t] = (t < 144) ? offb[t] : maskb[t - 144];
        else if (t < 224) bcat[t] = 0.f;
    }
}

// ---------------- transpose NCHW -> NHWC ----------------
__global__ __launch_bounds__(256) void k_transpose(const float* __restrict__ in,
                                                   float* __restrict__ out){
    __shared__ float tile[64][65];
    const int b = blockIdx.z, c0 = blockIdx.y * 64, hw0 = blockIdx.x * 64;
    const int tx = threadIdx.x & 63, tg = threadIdx.x >> 6;
    #pragma unroll
    for (int i = 0; i < 16; i++){
        const int c_l = tg * 16 + i;
        tile[c_l][tx] = in[(size_t)(b * CCH + c0 + c_l) * HW + hw0 + tx];
    }
    __syncthreads();
    #pragma unroll
    for (int i = 0; i < 16; i++){
        const int hw_l = tg * 16 + i;
        out[(size_t)(b * HW + hw0 + hw_l) * CCH + c0 + tx] = tile[tx][hw_l];
    }
}

// ---------------- bf16 split-3 MFMA GEMM: out(16384 x M) = A(16384 x 256) @ W(256 x M) ------
// Tile 32(rows) x 256(cols) — A split ONCE per element. Grid 512 blocks.
// 4 waves in 2x2 quadrants of (16 rows x 128 cols); acc[8] f32x4.
// Frag layouts (verified r5): A/B in: idx=lane&15, k=8*(lane>>4)+j ; C/D: col=lane&15, row=4*(lane>>4)+reg
// EPI: 0 = bias, 1 = bias+gelu, 2 = bias + residual + NCHW write. MUL: A *= A2 elementwise.
template<int EPI, bool MUL>
__global__ __launch_bounds__(256) void k_gemm_bf(
    const float* __restrict__ A, const float* __restrict__ A2,
    const unsigned short* __restrict__ Whi, const unsigned short* __restrict__ Wlo,
    const float* __restrict__ bias, const float* __restrict__ resid,
    float* __restrict__ out, const int M, const int ldc)
{
    const int rows0 = blockIdx.x * 32;
    const int lane = threadIdx.x & 63;
    const int w    = threadIdx.x >> 6;
    const int wm = (w >> 1) * 16;   // row quadrant 0/16
    const int wn = (w & 1) * 128;   // col quadrant 0/128
    const int lr = lane & 15;
    const int kg = lane >> 4;
    const int kl = kg * 8;

    const float* Ap = A + (size_t)(rows0 + wm + lr) * 256 + kl;
    const float* Mp = MUL ? (A2 + (size_t)(rows0 + wm + lr) * 256 + kl) : nullptr;
    const int c0 = wn + lr;
    const unsigned short* Wh = Whi + (size_t)c0 * 256 + kl;
    const unsigned short* Wl = Wlo + (size_t)c0 * 256 + kl;

    const f32x4 z = {0.f, 0.f, 0.f, 0.f};
    f32x4 acc[8] = {z,z,z,z,z,z,z,z};

    #pragma unroll 2
    for (int kt = 0; kt < 8; kt++){
        const int k0 = kt * 32;
        float4 a0 = *reinterpret_cast<const float4*>(Ap + k0);
        float4 a1 = *reinterpret_cast<const float4*>(Ap + k0 + 4);
        if (MUL){
            const float4 u0 = *reinterpret_cast<const float4*>(Mp + k0);
            const float4 u1 = *reinterpret_cast<const float4*>(Mp + k0 + 4);
            a0.x*=u0.x; a0.y*=u0.y; a0.z*=u0.z; a0.w*=u0.w;
            a1.x*=u1.x; a1.y*=u1.y; a1.z*=u1.z; a1.w*=u1.w;
        }
        bf16x8 ah, al;
        split_cheap(a0, a1, ah, al);
        #pragma unroll
        for (int nf = 0; nf < 8; nf++){
            const size_t wo = (size_t)(nf * 16) * 256 + k0;
            const bf16x8 bh = *reinterpret_cast<const bf16x8*>(Wh + wo);
            const bf16x8 bl = *reinterpret_cast<const bf16x8*>(Wl + wo);
            acc[nf] = __builtin_amdgcn_mfma_f32_16x16x32_bf16(ah, bh, acc[nf], 0, 0, 0);
            acc[nf] = __builtin_amdgcn_mfma_f32_16x16x32_bf16(ah, bl, acc[nf], 0, 0, 0);
            acc[nf] = __builtin_amdgcn_mfma_f32_16x16x32_bf16(al, bh, acc[nf], 0, 0, 0);
        }
    }

    const int r4 = kg * 4;
    const int rowb = rows0 + wm + r4;
    if (EPI == 2){
        const int bimg = rowb >> 12;
        const int hw   = rowb & (HW - 1);
        #pragma unroll
        for (int nf = 0; nf < 8; nf++){
            const int col = c0 + nf * 16;
            const float bs = bias[col];
            const size_t addr = ((size_t)(bimg * CCH + col)) * HW + hw;
            const float4 rv = *reinterpret_cast<const float4*>(resid + addr);
            float4 o;
            o.x = acc[nf][0] + bs + rv.x;
            o.y = acc[nf][1] + bs + rv.y;
            o.z = acc[nf][2] + bs + rv.z;
            o.w = acc[nf][3] + bs + rv.w;
            *reinterpret_cast<float4*>(out + addr) = o;
        }
    } else {
        #pragma unroll
        for (int nf = 0; nf < 8; nf++){
            const int col = c0 + nf * 16;
            if (col < M){
                const float bs = bias[col];
                #pragma unroll
                for (int r = 0; r < 4; r++){
                    float v = acc[nf][r] + bs;
                    if (EPI == 1) v = gelu_f(v);
                    out[(size_t)(rowb + r) * ldc + col] = v;
                }
            }
        }
    }
}

// ---------------- depthwise 5x5, pad 2, NHWC — branchless, float4 channels ----------------
__global__ __launch_bounds__(256) void k_dwconv5(const float* __restrict__ in,
                                                 const float* __restrict__ wT,
                                                 const float* __restrict__ bias,
                                                 float* __restrict__ out){
    const int lane = threadIdx.x & 63;
    const int pq   = threadIdx.x >> 6;
    const int n = blockIdx.x * 4 + pq;
    const int x = n & 63, y = (n >> 6) & 63, b = n >> 12;
    const int c = lane * 4;
    const float* bp = in + (size_t)(b * HW) * CCH + c;
    float4 acc = *reinterpret_cast<const float4*>(bias + c);
    #pragma unroll
    for (int k = 0; k < 25; k++){
        const int dy = k / 5 - 2, dx = k % 5 - 2;
        const int yy = y + dy, xx = x + dx;
        const float m = (((unsigned)yy < 64u) & ((unsigned)xx < 64u)) ? 1.f : 0.f;
        const int yc = min(max(yy, 0), 63), xc = min(max(xx, 0), 63);
        const float4 iv = *reinterpret_cast<const float4*>(bp + (size_t)(yc * 64 + xc) * CCH);
        const float4 wv = *reinterpret_cast<const float4*>(wT + k * CCH + c);
        acc.x = fmaf(iv.x, wv.x * m, acc.x);
        acc.y = fmaf(iv.y, wv.y * m, acc.y);
        acc.z = fmaf(iv.z, wv.z * m, acc.z);
        acc.w = fmaf(iv.w, wv.w * m, acc.w);
    }
    *reinterpret_cast<float4*>(out + (size_t)n * CCH + c) = acc;
}

// ---------------- depthwise 3x3 + LayerNorm(channel) + GELU — branchless, wave-reduce ------
__global__ __launch_bounds__(256) void k_dw3_ln_gelu(const float* __restrict__ in,
                                                     const float* __restrict__ wT3,
                                                     const float* __restrict__ b3,
                                                     const float* __restrict__ g,
                                                     const float* __restrict__ bta,
                                                     float* __restrict__ out){
    const int lane = threadIdx.x & 63;
    const int pq   = threadIdx.x >> 6;
    const int n = blockIdx.x * 4 + pq;
    const int x = n & 63, y = (n >> 6) & 63, b = n >> 12;
    const int c = lane * 4;
    const float* bp = in + (size_t)(b * HW) * CCH + c;
    float4 acc = *reinterpret_cast<const float4*>(b3 + c);
    #pragma unroll
    for (int k = 0; k < 9; k++){
        const int dy = k / 3 - 1, dx = k % 3 - 1;
        const int yy = y + dy, xx = x + dx;
        const float m = (((unsigned)yy < 64u) & ((unsigned)xx < 64u)) ? 1.f : 0.f;
        const int yc = min(max(yy, 0), 63), xc = min(max(xx, 0), 63);
        const float4 iv = *reinterpret_cast<const float4*>(bp + (size_t)(yc * 64 + xc) * CCH);
        const float4 wv = *reinterpret_cast<const float4*>(wT3 + k * CCH + c);
        acc.x = fmaf(iv.x, wv.x * m, acc.x);
        acc.y = fmaf(iv.y, wv.y * m, acc.y);
        acc.z = fmaf(iv.z, wv.z * m, acc.z);
        acc.w = fmaf(iv.w, wv.w * m, acc.w);
    }
    float s  = acc.x + acc.y + acc.z + acc.w;
    float s2 = acc.x*acc.x + acc.y*acc.y + acc.z*acc.z + acc.w*acc.w;
    #pragma unroll
    for (int o = 32; o > 0; o >>= 1){
        s  += __shfl_xor(s, o);
        s2 += __shfl_xor(s2, o);
    }
    const float mu  = s  * (1.f / 256.f);
    const float var = s2 * (1.f / 256.f) - mu * mu;
    const float r   = rsqrtf(var + 1e-5f);
    const float4 gv = *reinterpret_cast<const float4*>(g + c);
    const float4 bv = *reinterpret_cast<const float4*>(bta + c);
    float4 o;
    o.x = gelu_f((acc.x - mu) * r * gv.x + bv.x);
    o.y = gelu_f((acc.y - mu) * r * gv.y + bv.y);
    o.z = gelu_f((acc.z - mu) * r * gv.z + bv.z);
    o.w = gelu_f((acc.w - mu) * r * gv.w + bv.w);
    *reinterpret_cast<float4*>(out + (size_t)n * CCH + c) = o;
}

// ---------------- DCNv3 core: fused softmax + bilinear sample + mask-weighted sum ----------
__global__ __launch_bounds__(256) void k_dcn(const float* __restrict__ xproj,
                                             const float* __restrict__ om,
                                             float* __restrict__ out){
    const int lane = threadIdx.x & 63;
    const int pq   = threadIdx.x >> 6;
    const int n = blockIdx.x * 4 + pq;
    const int gI = lane >> 3, cq = lane & 7;
    const int x = n & 63, y = (n >> 6) & 63, b = n >> 12;
    const float* off = om + (size_t)n * 216 + gI * 18;
    const float* lg  = om + (size_t)n * 216 + 144 + gI * 9;
    float l[9]; float mx = -1e30f;
    #pragma unroll
    for (int p = 0; p < 9; p++){ l[p] = lg[p]; mx = fmaxf(mx, l[p]); }
    float ssum = 0.f;
    #pragma unroll
    for (int p = 0; p < 9; p++){ l[p] = expf(l[p] - mx); ssum += l[p]; }
    const float inv = 1.f / ssum;
    const float* base = xproj + (size_t)b * HW * CCH + gI * 32 + cq * 4;
    float4 acc = {0.f, 0.f, 0.f, 0.f};
    #pragma unroll
    for (int p = 0; p < 9; p++){
        const float2 o2 = *reinterpret_cast<const float2*>(off + p * 2);
        const float ix = (float)(x + p / 3) + o2.x;
        const float iy = (float)(y + p % 3) + o2.y;
        const float x0f = floorf(ix), y0f = floorf(iy);
        const float wx1 = ix - x0f, wy1 = iy - y0f;
        const float wx0 = 1.f - wx1, wy0 = 1.f - wy1;
        const int ux = (int)x0f - 1, uy = (int)y0f - 1;
        const bool X0 = (unsigned)ux     < 64u, X1 = (unsigned)(ux+1) < 64u;
        const bool Y0 = (unsigned)uy     < 64u, Y1 = (unsigned)(uy+1) < 64u;
        const int ux0 = min(max(ux,     0), 63), ux1 = min(max(ux + 1, 0), 63);
        const int uy0 = min(max(uy,     0), 63), uy1 = min(max(uy + 1, 0), 63);
        const float mp = l[p] * inv;
        const float w00 = wx0 * wy0 * ((X0 & Y0) ? mp : 0.f);
        const float w01 = wx1 * wy0 * ((X1 & Y0) ? mp : 0.f);
        const float w10 = wx0 * wy1 * ((X0 & Y1) ? mp : 0.f);
        const float w11 = wx1 * wy1 * ((X1 & Y1) ? mp : 0.f);
        const float4 v00 = *reinterpret_cast<const float4*>(base + (size_t)(uy0 * 64 + ux0) * CCH);
        const float4 v01 = *reinterpret_cast<const float4*>(base + (size_t)(uy0 * 64 + ux1) * CCH);
        const float4 v10 = *reinterpret_cast<const float4*>(base + (size_t)(uy1 * 64 + ux0) * CCH);
        const float4 v11 = *reinterpret_cast<const float4*>(base + (size_t)(uy1 * 64 + ux1) * CCH);
        acc.x = fmaf(w00, v00.x, fmaf(w01, v01.x, fmaf(w10, v10.x, fmaf(w11, v11.x, acc.x))));
        acc.y = fmaf(w00, v00.y, fmaf(w01, v01.y, fmaf(w10, v10.y, fmaf(w11, v11.y, acc.y))));
        acc.z = fmaf(w00, v00.z, fmaf(w01, v01.z, fmaf(w10, v10.z, fmaf(w11, v11.z, acc.z))));
        acc.w = fmaf(w00, v00.w, fmaf(w01, v01.w, fmaf(w10, v10.w, fmaf(w11, v11.w, acc.w))));
    }
    *reinterpret_cast<float4*>(out + (size_t)n * CCH + gI * 32 + cq * 4) = acc;
}

extern "C" void kernel_launch(void* const* d_in, const int* in_sizes, int n_in,
                              void* d_out, int out_size, void* d_ws, size_t ws_size,
                              hipStream_t stream){
    const float* x         = (const float*)d_in[0];
    const float* proj1_w   = (const float*)d_in[1];
    const float* proj1_b   = (const float*)d_in[2];
    const float* conv0_w   = (const float*)d_in[3];
    const float* conv0_b   = (const float*)d_in[4];
    const float* inproj_w  = (const float*)d_in[5];
    const float* inproj_b  = (const float*)d_in[6];
    const float* dw_w      = (const float*)d_in[7];
    const float* dw_b      = (const float*)d_in[8];
    const float* ln_g      = (const float*)d_in[9];
    const float* ln_b      = (const float*)d_in[10];
    const float* off_w     = (const float*)d_in[11];
    const float* off_b     = (const float*)d_in[12];
    const float* mask_w    = (const float*)d_in[13];
    const float* mask_b    = (const float*)d_in[14];
    const float* outproj_w = (const float*)d_in[15];
    const float* outproj_b = (const float*)d_in[16];
    const float* conv_w    = (const float*)d_in[17];
    const float* conv_b    = (const float*)d_in[18];
    const float* proj2_w   = (const float*)d_in[19];
    const float* proj2_b   = (const float*)d_in[20];
    float* outp = (float*)d_out;

    const size_t NC = (size_t)NPIX * CCH;
    float* b0 = (float*)d_ws;      // x_t -> x1 -> dcnout
    float* b1 = b0 + NC;           // u (persists to the end)
    float* b2 = b1 + NC;           // h5 -> offset/mask(om) -> attn2
    float* b3 = outp;              // d_out as scratch: conv-wT -> xproj -> final
    unsigned short* wsp = (unsigned short*)(b2 + NC);   // 5 pairs of 256x256 bf16 hi/lo
    float* bcat = (float*)(wsp + 5 * 131072);           // 224 floats (off_b ++ mask_b ++ 0)
    float* woc  = bcat + 224;                           // 256x256 fp32 composed weight
    float* boc  = woc + 65536;                          // 256 fp32 composed bias
    float* wT   = b3;              // 25x256 conv5 weights (dead before xproj)
    float* wT3  = b3 + 25 * CCH;   // 9x256 conv3 weights

    const unsigned short* whi[5]; const unsigned short* wlo[5];
    for (int i = 0; i < 5; i++){ whi[i] = wsp + (size_t)i * 131072; wlo[i] = whi[i] + 65536; }

    // 0. weight preps: conv transposes; woc = outproj@conv fold; split all 5 GEMM weights
    k_prep<<<25,256,0,stream>>>(conv0_w, dw_w, wT, wT3);
    k_compose<<<257,256,0,stream>>>(outproj_w, conv_w, outproj_b, conv_b, woc, boc);
    k_prep_w<<<dim3(16,5),256,0,stream>>>(proj1_w, inproj_w, woc, proj2_w,
                                          off_w, mask_w, off_b, mask_b, wsp, bcat);
    // 1. x (NCHW) -> NHWC
    k_transpose<<<dim3(64,4,4),256,0,stream>>>(x, b0);
    // 2. u = gelu(x @ proj1_w + b)
    k_gemm_bf<1,false><<<512,256,0,stream>>>(b0, nullptr, whi[0], wlo[0], proj1_b, nullptr, b1, 256, 256);
    // 3. h5 = dwconv5x5(u)
    k_dwconv5<<<4096,256,0,stream>>>(b1, wT, conv0_b, b2);
    // 4. x1 = gelu(LN(dwconv3x3(h5)))  (before xproj overwrites d_out head)
    k_dw3_ln_gelu<<<4096,256,0,stream>>>(b2, wT3, dw_b, ln_g, ln_b, b0);
    // 5. xproj = h5 @ inproj_w + b  -> d_out scratch
    k_gemm_bf<0,false><<<512,256,0,stream>>>(b2, nullptr, whi[1], wlo[1], inproj_b, nullptr, b3, 256, 256);
    // 6. offset||mask logits = x1 @ [off_w|mask_w] + b  (M=216, ld 216) into b2
    k_gemm_bf<0,false><<<512,256,0,stream>>>(b0, nullptr, whi[4], wlo[4], bcat, nullptr, b2, 216, 216);
    // 7. DCN core (softmax fused)
    k_dcn<<<4096,256,0,stream>>>(b3, b2, b0);
    // 8. attn2 = dcnout @ woc + boc   (outproj and conv folded into one GEMM)
    k_gemm_bf<0,false><<<512,256,0,stream>>>(b0, nullptr, whi[2], wlo[2], boc, nullptr, b2, 256, 256);
    // 9. out = (u * attn2) @ proj2_w + b + x   (NCHW write, fused residual)
    k_gemm_bf<2,true><<<512,256,0,stream>>>(b1, b2, whi[3], wlo[3], proj2_b, x, outp, 256, 256);
}

// Round 13
// 346.737 us; speedup vs baseline: 1.1290x; 1.1290x over previous
//
#include <hip/hip_runtime.h>
#include <cstddef>

#define HW    4096
#define NPIX  16384
#define CCH   256

typedef __attribute__((ext_vector_type(8))) short bf16x8;
typedef __attribute__((ext_vector_type(4))) float f32x4;

__device__ __forceinline__ float gelu_f(float x){
    return 0.5f * x * (1.0f + erff(x * 0.70710678118654752f));
}

__device__ __forceinline__ unsigned short bf_rne(float f){
    unsigned u = __float_as_uint(f);
    u += 0x7FFFu + ((u >> 16) & 1u);
    return (unsigned short)(u >> 16);
}

// RNE split: hi = trunc_bf16(f), lo = rne_bf16(f - hi); hi+lo carries ~16-17 mantissa bits
__device__ __forceinline__ void split2(const float4 a, const float4 b, bf16x8& hi, bf16x8& lo){
    const float v[8] = {a.x,a.y,a.z,a.w,b.x,b.y,b.z,b.w};
    #pragma unroll
    for (int j = 0; j < 8; j++){
        const unsigned u = __float_as_uint(v[j]);
        hi[j] = (short)(unsigned short)(u >> 16);
        lo[j] = (short)bf_rne(v[j] - __uint_as_float(u & 0xFFFF0000u));
    }
}

// ---------------- conv-weight transpose: one tap per block ----------------
__global__ __launch_bounds__(256) void k_prep(const float* __restrict__ w5,
                                              const float* __restrict__ w3,
                                              float* __restrict__ wT,
                                              float* __restrict__ wT3){
    const int c = threadIdx.x;
    const int j = blockIdx.x;
    wT[j * CCH + c] = w5[c * 25 + j];
    if (j < 9) wT3[j * CCH + c] = w3[c * 9 + j];
}

// ---------------- weight composition: woc = outproj_w @ conv_w ; boc = outproj_b @ conv_w + conv_b
__global__ __launch_bounds__(256) void k_compose(const float* __restrict__ ow,
                                                 const float* __restrict__ cw,
                                                 const float* __restrict__ ob,
                                                 const float* __restrict__ cb,
                                                 float* __restrict__ woc,
                                                 float* __restrict__ boc){
    const int m = threadIdx.x;
    if (blockIdx.x == 256){
        float acc = cb[m];
        #pragma unroll 4
        for (int k = 0; k < 256; k++) acc = fmaf(ob[k], cw[k * 256 + m], acc);
        boc[m] = acc;
    } else {
        const int r = blockIdx.x;
        const float* orow = ow + r * 256;
        float acc = 0.f;
        #pragma unroll 4
        for (int k = 0; k < 256; k++) acc = fmaf(orow[k], cw[k * 256 + m], acc);
        woc[r * 256 + m] = acc;
    }
}

// ---------------- GEMM-weight prep: W[k][m] fp32 -> W_T[m][k] bf16 hi/lo, LDS-tiled ---------
// grid (16, 5): blockIdx.y = matrix id (0=proj1,1=inproj,2=woc,3=proj2,4=off||mask concat)
__global__ __launch_bounds__(256) void k_prep_w(
    const float* __restrict__ w0, const float* __restrict__ w1, const float* __restrict__ w2,
    const float* __restrict__ w3,
    const float* __restrict__ offw, const float* __restrict__ maskw,
    const float* __restrict__ offb, const float* __restrict__ maskb,
    unsigned short* __restrict__ wsp, float* __restrict__ bcat)
{
    __shared__ float tile[64][65];
    const int id = blockIdx.y;
    const int m0 = (blockIdx.x & 3) * 64;
    const int k0 = (blockIdx.x >> 2) * 64;
    const int tx = threadIdx.x & 63, tg = threadIdx.x >> 6;
    unsigned short* hi = wsp + (size_t)id * 131072;
    unsigned short* lo = hi + 65536;

    const int m = m0 + tx;
    const float* src = nullptr; int stride = 0; bool valid = true;
    if (id == 4){
        if (m < 144){ src = offw + m; stride = 144; }
        else if (m < 216){ src = maskw + (m - 144); stride = 72; }
        else valid = false;
    } else {
        const float* s = (id==0)?w0:(id==1)?w1:(id==2)?w2:w3;
        src = s + m; stride = 256;
    }
    #pragma unroll
    for (int i = 0; i < 16; i++){
        const int kl = tg * 16 + i;
        tile[kl][tx] = valid ? src[(size_t)(k0 + kl) * stride] : 0.f;
    }
    __syncthreads();
    #pragma unroll
    for (int i = 0; i < 16; i++){
        const int ml = tg * 16 + i;
        const float f = tile[tx][ml];
        const unsigned u = __float_as_uint(f);
        const size_t o = (size_t)(m0 + ml) * 256 + k0 + tx;
        hi[o] = (unsigned short)(u >> 16);
        lo[o] = bf_rne(f - __uint_as_float(u & 0xFFFF0000u));
    }
    if (id == 4 && blockIdx.x == 0){
        const int t = threadIdx.x;
        if (t < 216) bcat[t] = (t < 144) ? offb[t] : maskb[t - 144];
        else if (t < 224) bcat[t] = 0.f;
    }
}

// ---------------- transpose NCHW -> NHWC ----------------
__global__ __launch_bounds__(256) void k_transpose(const float* __restrict__ in,
                                                   float* __restrict__ out){
    __shared__ float tile[64][65];
    const int b = blockIdx.z, c0 = blockIdx.y * 64, hw0 = blockIdx.x * 64;
    const int tx = threadIdx.x & 63, tg = threadIdx.x >> 6;
    #pragma unroll
    for (int i = 0; i < 16; i++){
        const int c_l = tg * 16 + i;
        tile[c_l][tx] = in[(size_t)(b * CCH + c0 + c_l) * HW + hw0 + tx];
    }
    __syncthreads();
    #pragma unroll
    for (int i = 0; i < 16; i++){
        const int hw_l = tg * 16 + i;
        out[(size_t)(b * HW + hw0 + hw_l) * CCH + c0 + tx] = tile[tx][hw_l];
    }
}

// ---------------- bf16 split-3 MFMA GEMM: out(16384 x M) = A(16384 x 256) @ W(256 x M) ------
// Tile 64(rows) x 128(cols), 4 waves in 2x2 quadrants of 32x64 (round-5 geometry, best measured).
// EPI 0/1: SWAPPED operands mfma(w,a) -> lane holds 4 consecutive out-cols -> float4 stores.
// EPI 2:   unswapped -> lane holds 4 consecutive rows (hw) -> float4 NCHW stores (r11-validated).
// Loads identical either way: A/B frag layout idx=lane&15, k=8*(lane>>4)+j; C/D col=lane&15, row=4*(lane>>4)+reg.
template<int EPI, bool MUL>
__global__ __launch_bounds__(256) void k_gemm_bf(
    const float* __restrict__ A, const float* __restrict__ A2,
    const unsigned short* __restrict__ Whi, const unsigned short* __restrict__ Wlo,
    const float* __restrict__ bias, const float* __restrict__ resid,
    float* __restrict__ out, const int M, const int ldc)
{
    const int rows0 = blockIdx.x * 64;
    const int cols0 = blockIdx.y * 128;
    const int lane = threadIdx.x & 63;
    const int w    = threadIdx.x >> 6;
    const int wm = (w >> 1) * 32, wn = (w & 1) * 64;
    const int lr = lane & 15;
    const int kg = lane >> 4;
    const int kl = kg * 8;

    const float* Ap0 = A + (size_t)(rows0 + wm + lr) * 256 + kl;
    const float* Ap1 = Ap0 + 16 * 256;
    const float* Mp0 = MUL ? (A2 + (size_t)(rows0 + wm + lr) * 256 + kl) : nullptr;
    const float* Mp1 = MUL ? (Mp0 + 16 * 256) : nullptr;
    const int cw = cols0 + wn + lr;
    const unsigned short* Wh = Whi + (size_t)cw * 256 + kl;
    const unsigned short* Wl = Wlo + (size_t)cw * 256 + kl;

    const f32x4 z = {0.f, 0.f, 0.f, 0.f};
    f32x4 acc[2][4] = {{z,z,z,z},{z,z,z,z}};

    #pragma unroll 2
    for (int kt = 0; kt < 8; kt++){
        const int k0 = kt * 32;
        float4 a0 = *reinterpret_cast<const float4*>(Ap0 + k0);
        float4 a1 = *reinterpret_cast<const float4*>(Ap0 + k0 + 4);
        float4 a2 = *reinterpret_cast<const float4*>(Ap1 + k0);
        float4 a3 = *reinterpret_cast<const float4*>(Ap1 + k0 + 4);
        if (MUL){
            const float4 u0 = *reinterpret_cast<const float4*>(Mp0 + k0);
            const float4 u1 = *reinterpret_cast<const float4*>(Mp0 + k0 + 4);
            const float4 u2 = *reinterpret_cast<const float4*>(Mp1 + k0);
            const float4 u3 = *reinterpret_cast<const float4*>(Mp1 + k0 + 4);
            a0.x*=u0.x; a0.y*=u0.y; a0.z*=u0.z; a0.w*=u0.w;
            a1.x*=u1.x; a1.y*=u1.y; a1.z*=u1.z; a1.w*=u1.w;
            a2.x*=u2.x; a2.y*=u2.y; a2.z*=u2.z; a2.w*=u2.w;
            a3.x*=u3.x; a3.y*=u3.y; a3.z*=u3.z; a3.w*=u3.w;
        }
        bf16x8 ah0, al0, ah1, al1;
        split2(a0, a1, ah0, al0);
        split2(a2, a3, ah1, al1);
        #pragma unroll
        for (int c = 0; c < 4; c++){
            const size_t wo = (size_t)(c * 16) * 256 + k0;
            const bf16x8 bh = *reinterpret_cast<const bf16x8*>(Wh + wo);
            const bf16x8 bl = *reinterpret_cast<const bf16x8*>(Wl + wo);
            if (EPI == 2){
                acc[0][c] = __builtin_amdgcn_mfma_f32_16x16x32_bf16(ah0, bh, acc[0][c], 0, 0, 0);
                acc[0][c] = __builtin_amdgcn_mfma_f32_16x16x32_bf16(ah0, bl, acc[0][c], 0, 0, 0);
                acc[0][c] = __builtin_amdgcn_mfma_f32_16x16x32_bf16(al0, bh, acc[0][c], 0, 0, 0);
                acc[1][c] = __builtin_amdgcn_mfma_f32_16x16x32_bf16(ah1, bh, acc[1][c], 0, 0, 0);
                acc[1][c] = __builtin_amdgcn_mfma_f32_16x16x32_bf16(ah1, bl, acc[1][c], 0, 0, 0);
                acc[1][c] = __builtin_amdgcn_mfma_f32_16x16x32_bf16(al1, bh, acc[1][c], 0, 0, 0);
            } else {
                acc[0][c] = __builtin_amdgcn_mfma_f32_16x16x32_bf16(bh, ah0, acc[0][c], 0, 0, 0);
                acc[0][c] = __builtin_amdgcn_mfma_f32_16x16x32_bf16(bh, al0, acc[0][c], 0, 0, 0);
                acc[0][c] = __builtin_amdgcn_mfma_f32_16x16x32_bf16(bl, ah0, acc[0][c], 0, 0, 0);
                acc[1][c] = __builtin_amdgcn_mfma_f32_16x16x32_bf16(bh, ah1, acc[1][c], 0, 0, 0);
                acc[1][c] = __builtin_amdgcn_mfma_f32_16x16x32_bf16(bh, al1, acc[1][c], 0, 0, 0);
                acc[1][c] = __builtin_amdgcn_mfma_f32_16x16x32_bf16(bl, ah1, acc[1][c], 0, 0, 0);
            }
        }
    }

    const int r4 = kg * 4;
    if (EPI == 2){
        // unswapped: lane col m = cw + c*16, rows n = rows0+wm+f*16+r4+r (contiguous hw)
        #pragma unroll
        for (int f = 0; f < 2; f++){
            const int n = rows0 + wm + f * 16 + r4;
            const int bimg = n >> 12;
            const int hw = n & (HW - 1);
            #pragma unroll
            for (int c = 0; c < 4; c++){
                const int col = cw + c * 16;
                const float bs = bias[col];
                const size_t addr = ((size_t)(bimg * CCH + col)) * HW + hw;
                const float4 rv = *reinterpret_cast<const float4*>(resid + addr);
                float4 o;
                o.x = acc[f][c][0] + bs + rv.x;
                o.y = acc[f][c][1] + bs + rv.y;
                o.z = acc[f][c][2] + bs + rv.z;
                o.w = acc[f][c][3] + bs + rv.w;
                *reinterpret_cast<float4*>(out + addr) = o;
            }
        }
    } else {
        // swapped: lane row n = rows0+wm+f*16+lr, cols m = cols0+wn+c*16+r4 .. +3 (contiguous)
        #pragma unroll
        for (int f = 0; f < 2; f++){
            const int n = rows0 + wm + f * 16 + lr;
            #pragma unroll
            for (int c = 0; c < 4; c++){
                const int mb = cols0 + wn + c * 16 + r4;
                if (mb < M){
                    const float4 bv = *reinterpret_cast<const float4*>(bias + mb);
                    float4 o;
                    o.x = acc[f][c][0] + bv.x;
                    o.y = acc[f][c][1] + bv.y;
                    o.z = acc[f][c][2] + bv.z;
                    o.w = acc[f][c][3] + bv.w;
                    if (EPI == 1){ o.x=gelu_f(o.x); o.y=gelu_f(o.y); o.z=gelu_f(o.z); o.w=gelu_f(o.w); }
                    *reinterpret_cast<float4*>(out + (size_t)n * ldc + mb) = o;
                }
            }
        }
    }
}

// ---------------- depthwise 5x5, pad 2, NHWC — branchless, float4 channels ----------------
__global__ __launch_bounds__(256) void k_dwconv5(const float* __restrict__ in,
                                                 const float* __restrict__ wT,
                                                 const float* __restrict__ bias,
                                                 float* __restrict__ out){
    const int lane = threadIdx.x & 63;
    const int pq   = threadIdx.x >> 6;
    const int n = blockIdx.x * 4 + pq;
    const int x = n & 63, y = (n >> 6) & 63, b = n >> 12;
    const int c = lane * 4;
    const float* bp = in + (size_t)(b * HW) * CCH + c;
    float4 acc = *reinterpret_cast<const float4*>(bias + c);
    #pragma unroll
    for (int k = 0; k < 25; k++){
        const int dy = k / 5 - 2, dx = k % 5 - 2;
        const int yy = y + dy, xx = x + dx;
        const float m = (((unsigned)yy < 64u) & ((unsigned)xx < 64u)) ? 1.f : 0.f;
        const int yc = min(max(yy, 0), 63), xc = min(max(xx, 0), 63);
        const float4 iv = *reinterpret_cast<const float4*>(bp + (size_t)(yc * 64 + xc) * CCH);
        const float4 wv = *reinterpret_cast<const float4*>(wT + k * CCH + c);
        acc.x = fmaf(iv.x, wv.x * m, acc.x);
        acc.y = fmaf(iv.y, wv.y * m, acc.y);
        acc.z = fmaf(iv.z, wv.z * m, acc.z);
        acc.w = fmaf(iv.w, wv.w * m, acc.w);
    }
    *reinterpret_cast<float4*>(out + (size_t)n * CCH + c) = acc;
}

// ---------------- depthwise 3x3 + LayerNorm(channel) + GELU — branchless, wave-reduce ------
__global__ __launch_bounds__(256) void k_dw3_ln_gelu(const float* __restrict__ in,
                                                     const float* __restrict__ wT3,
                                                     const float* __restrict__ b3,
                                                     const float* __restrict__ g,
                                                     const float* __restrict__ bta,
                                                     float* __restrict__ out){
    const int lane = threadIdx.x & 63;
    const int pq   = threadIdx.x >> 6;
    const int n = blockIdx.x * 4 + pq;
    const int x = n & 63, y = (n >> 6) & 63, b = n >> 12;
    const int c = lane * 4;
    const float* bp = in + (size_t)(b * HW) * CCH + c;
    float4 acc = *reinterpret_cast<const float4*>(b3 + c);
    #pragma unroll
    for (int k = 0; k < 9; k++){
        const int dy = k / 3 - 1, dx = k % 3 - 1;
        const int yy = y + dy, xx = x + dx;
        const float m = (((unsigned)yy < 64u) & ((unsigned)xx < 64u)) ? 1.f : 0.f;
        const int yc = min(max(yy, 0), 63), xc = min(max(xx, 0), 63);
        const float4 iv = *reinterpret_cast<const float4*>(bp + (size_t)(yc * 64 + xc) * CCH);
        const float4 wv = *reinterpret_cast<const float4*>(wT3 + k * CCH + c);
        acc.x = fmaf(iv.x, wv.x * m, acc.x);
        acc.y = fmaf(iv.y, wv.y * m, acc.y);
        acc.z = fmaf(iv.z, wv.z * m, acc.z);
        acc.w = fmaf(iv.w, wv.w * m, acc.w);
    }
    float s  = acc.x + acc.y + acc.z + acc.w;
    float s2 = acc.x*acc.x + acc.y*acc.y + acc.z*acc.z + acc.w*acc.w;
    #pragma unroll
    for (int o = 32; o > 0; o >>= 1){
        s  += __shfl_xor(s, o);
        s2 += __shfl_xor(s2, o);
    }
    const float mu  = s  * (1.f / 256.f);
    const float var = s2 * (1.f / 256.f) - mu * mu;
    const float r   = rsqrtf(var + 1e-5f);
    const float4 gv = *reinterpret_cast<const float4*>(g + c);
    const float4 bv = *reinterpret_cast<const float4*>(bta + c);
    float4 o;
    o.x = gelu_f((acc.x - mu) * r * gv.x + bv.x);
    o.y = gelu_f((acc.y - mu) * r * gv.y + bv.y);
    o.z = gelu_f((acc.z - mu) * r * gv.z + bv.z);
    o.w = gelu_f((acc.w - mu) * r * gv.w + bv.w);
    *reinterpret_cast<float4*>(out + (size_t)n * CCH + c) = o;
}

// ---------------- DCNv3 core: fused softmax + bilinear sample + mask-weighted sum ----------
__global__ __launch_bounds__(256) void k_dcn(const float* __restrict__ xproj,
                                             const float* __restrict__ om,
                                             float* __restrict__ out){
    const int lane = threadIdx.x & 63;
    const int pq   = threadIdx.x >> 6;
    const int n = blockIdx.x * 4 + pq;
    const int gI = lane >> 3, cq = lane & 7;
    const int x = n & 63, y = (n >> 6) & 63, b = n >> 12;
    const float* off = om + (size_t)n * 216 + gI * 18;
    const float* lg  = om + (size_t)n * 216 + 144 + gI * 9;
    float l[9]; float mx = -1e30f;
    #pragma unroll
    for (int p = 0; p < 9; p++){ l[p] = lg[p]; mx = fmaxf(mx, l[p]); }
    float ssum = 0.f;
    #pragma unroll
    for (int p = 0; p < 9; p++){ l[p] = expf(l[p] - mx); ssum += l[p]; }
    const float inv = 1.f / ssum;
    const float* base = xproj + (size_t)b * HW * CCH + gI * 32 + cq * 4;
    float4 acc = {0.f, 0.f, 0.f, 0.f};
    #pragma unroll
    for (int p = 0; p < 9; p++){
        const float2 o2 = *reinterpret_cast<const float2*>(off + p * 2);
        const float ix = (float)(x + p / 3) + o2.x;
        const float iy = (float)(y + p % 3) + o2.y;
        const float x0f = floorf(ix), y0f = floorf(iy);
        const float wx1 = ix - x0f, wy1 = iy - y0f;
        const float wx0 = 1.f - wx1, wy0 = 1.f - wy1;
        const int ux = (int)x0f - 1, uy = (int)y0f - 1;
        const bool X0 = (unsigned)ux     < 64u, X1 = (unsigned)(ux+1) < 64u;
        const bool Y0 = (unsigned)uy     < 64u, Y1 = (unsigned)(uy+1) < 64u;
        const int ux0 = min(max(ux,     0), 63), ux1 = min(max(ux + 1, 0), 63);
        const int uy0 = min(max(uy,     0), 63), uy1 = min(max(uy + 1, 0), 63);
        const float mp = l[p] * inv;
        const float w00 = wx0 * wy0 * ((X0 & Y0) ? mp : 0.f);
        const float w01 = wx1 * wy0 * ((X1 & Y0) ? mp : 0.f);
        const float w10 = wx0 * wy1 * ((X0 & Y1) ? mp : 0.f);
        const float w11 = wx1 * wy1 * ((X1 & Y1) ? mp : 0.f);
        const float4 v00 = *reinterpret_cast<const float4*>(base + (size_t)(uy0 * 64 + ux0) * CCH);
        const float4 v01 = *reinterpret_cast<const float4*>(base + (size_t)(uy0 * 64 + ux1) * CCH);
        const float4 v10 = *reinterpret_cast<const float4*>(base + (size_t)(uy1 * 64 + ux0) * CCH);
        const float4 v11 = *reinterpret_cast<const float4*>(base + (size_t)(uy1 * 64 + ux1) * CCH);
        acc.x = fmaf(w00, v00.x, fmaf(w01, v01.x, fmaf(w10, v10.x, fmaf(w11, v11.x, acc.x))));
        acc.y = fmaf(w00, v00.y, fmaf(w01, v01.y, fmaf(w10, v10.y, fmaf(w11, v11.y, acc.y))));
        acc.z = fmaf(w00, v00.z, fmaf(w01, v01.z, fmaf(w10, v10.z, fmaf(w11, v11.z, acc.z))));
        acc.w = fmaf(w00, v00.w, fmaf(w01, v01.w, fmaf(w10, v10.w, fmaf(w11, v11.w, acc.w))));
    }
    *reinterpret_cast<float4*>(out + (size_t)n * CCH + gI * 32 + cq * 4) = acc;
}

extern "C" void kernel_launch(void* const* d_in, const int* in_sizes, int n_in,
                              void* d_out, int out_size, void* d_ws, size_t ws_size,
                              hipStream_t stream){
    const float* x         = (const float*)d_in[0];
    const float* proj1_w   = (const float*)d_in[1];
    const float* proj1_b   = (const float*)d_in[2];
    const float* conv0_w   = (const float*)d_in[3];
    const float* conv0_b   = (const float*)d_in[4];
    const float* inproj_w  = (const float*)d_in[5];
    const float* inproj_b  = (const float*)d_in[6];
    const float* dw_w      = (const float*)d_in[7];
    const float* dw_b      = (const float*)d_in[8];
    const float* ln_g      = (const float*)d_in[9];
    const float* ln_b      = (const float*)d_in[10];
    const float* off_w     = (const float*)d_in[11];
    const float* off_b     = (const float*)d_in[12];
    const float* mask_w    = (const float*)d_in[13];
    const float* mask_b    = (const float*)d_in[14];
    const float* outproj_w = (const float*)d_in[15];
    const float* outproj_b = (const float*)d_in[16];
    const float* conv_w    = (const float*)d_in[17];
    const float* conv_b    = (const float*)d_in[18];
    const float* proj2_w   = (const float*)d_in[19];
    const float* proj2_b   = (const float*)d_in[20];
    float* outp = (float*)d_out;

    const size_t NC = (size_t)NPIX * CCH;
    float* b0 = (float*)d_ws;      // x_t -> x1 -> dcnout
    float* b1 = b0 + NC;           // u (persists to the end)
    float* b2 = b1 + NC;           // h5 -> offset/mask(om) -> attn2
    float* b3 = outp;              // d_out as scratch: conv-wT -> xproj -> final
    unsigned short* wsp = (unsigned short*)(b2 + NC);   // 5 pairs of 256x256 bf16 hi/lo
    float* bcat = (float*)(wsp + 5 * 131072);           // 224 floats (off_b ++ mask_b ++ 0)
    float* woc  = bcat + 224;                           // 256x256 fp32 composed weight
    float* boc  = woc + 65536;                          // 256 fp32 composed bias
    float* wT   = b3;              // 25x256 conv5 weights (dead before xproj)
    float* wT3  = b3 + 25 * CCH;   // 9x256 conv3 weights

    const unsigned short* whi[5]; const unsigned short* wlo[5];
    for (int i = 0; i < 5; i++){ whi[i] = wsp + (size_t)i * 131072; wlo[i] = whi[i] + 65536; }

    const dim3 G(256, 2);

    // 0. weight preps: conv transposes; woc = outproj@conv fold; split all 5 GEMM weights
    k_prep<<<25,256,0,stream>>>(conv0_w, dw_w, wT, wT3);
    k_compose<<<257,256,0,stream>>>(outproj_w, conv_w, outproj_b, conv_b, woc, boc);
    k_prep_w<<<dim3(16,5),256,0,stream>>>(proj1_w, inproj_w, woc, proj2_w,
                                          off_w, mask_w, off_b, mask_b, wsp, bcat);
    // 1. x (NCHW) -> NHWC
    k_transpose<<<dim3(64,4,4),256,0,stream>>>(x, b0);
    // 2. u = gelu(x @ proj1_w + b)
    k_gemm_bf<1,false><<<G,256,0,stream>>>(b0, nullptr, whi[0], wlo[0], proj1_b, nullptr, b1, 256, 256);
    // 3. h5 = dwconv5x5(u)
    k_dwconv5<<<4096,256,0,stream>>>(b1, wT, conv0_b, b2);
    // 4. x1 = gelu(LN(dwconv3x3(h5)))  (before xproj overwrites d_out head)
    k_dw3_ln_gelu<<<4096,256,0,stream>>>(b2, wT3, dw_b, ln_g, ln_b, b0);
    // 5. xproj = h5 @ inproj_w + b  -> d_out scratch
    k_gemm_bf<0,false><<<G,256,0,stream>>>(b2, nullptr, whi[1], wlo[1], inproj_b, nullptr, b3, 256, 256);
    // 6. offset||mask logits = x1 @ [off_w|mask_w] + b  (M=216, ld 216) into b2
    k_gemm_bf<0,false><<<G,256,0,stream>>>(b0, nullptr, whi[4], wlo[4], bcat, nullptr, b2, 216, 216);
    // 7. DCN core (softmax fused)
    k_dcn<<<4096,256,0,stream>>>(b3, b2, b0);
    // 8. attn2 = dcnout @ woc + boc   (outproj and conv folded into one GEMM)
    k_gemm_bf<0,false><<<G,256,0,stream>>>(b0, nullptr, whi[2], wlo[2], boc, nullptr, b2, 256, 256);
    // 9. out = (u * attn2) @ proj2_w + b + x   (NCHW write, fused residual)
    k_gemm_bf<2,true><<<G,256,0,stream>>>(b1, b2, whi[3], wlo[3], proj2_b, x, outp, 256, 256);
}